// Round 9
// baseline (62.127 us; speedup 1.0000x reference)
//
#include <hip/hip_runtime.h>

// MultiVectorFieldModel: per-point routed tiny MLP (17 -> 6 -> 16), 65 models.
// fp32 weights in LDS as float4 chunks, model-minor: wlds[k4][model], k4=0..54
// over the 220-float record {W1(102), b1(6), W2(96), b2(16)}:
//   chunks 0..23  : W1 rows 0..15 (3 chunks = 2 rows per group)
//   chunk  24     : W1 row 16 (t row) j0..3
//   chunk  25     : {W1[100], W1[101], b1[0], b1[1]}
//   chunk  26     : b1[2..5]
//   chunks 27..50 : W2 row j = chunks 27+4j .. 27+4j+3 (d-major)
//   chunks 51..54 : b2
//
// R0-R7 evidence: ~46us invariant across table formats / pts-per-thread /
// block sizes; all pipes <=30%. Model: divergent-address ds_read_b128
// (64 distinct random addrs) costs ~20-24cy -> 55 gathers/pt = ~41us. R8:
// BLOCK-LOCAL COUNTING SORT by mid (LDS histogram + scan + scatter), then
// lane tid processes point bidx[tid] -> sorted mids -> ~4-5 distinct addrs
// per wave -> weight reads become near-broadcast (~8-10cy, conflict-free).
// x re-read is divergent within the block's 72KB window (L2-hot); stores
// scatter within 64KB but each lane writes its full 64B line.
// R3 lesson stands: never cap VGPR at 64 explicitly (spill disaster).

#define NMODELS 65
#define WPM 220
#define NCHUNK 55
#define BLOCK 1024

__global__ __launch_bounds__(BLOCK, 4) void mvf_kernel(
    const float* __restrict__ x,
    const float* __restrict__ W1,
    const float* __restrict__ b1,
    const float* __restrict__ W2,
    const float* __restrict__ b2,
    float* __restrict__ out,
    int npts)
{
    __shared__ float4 wlds[NCHUNK][NMODELS];   // 57200 B
    __shared__ unsigned bidx[BLOCK];           // 4096 B
    __shared__ int hist[NMODELS];              // 260 B
    __shared__ int base[NMODELS];              // 260 B

    const int tid = threadIdx.x;
    if (tid < NMODELS) hist[tid] = 0;

    const long pbase = (long)blockIdx.x * BLOCK;
    const int nvalid = min(BLOCK, npts - (int)pbase);
    const bool valid = tid < nvalid;

    // issue the routing load early; it drains under the staging loop
    float2 ct = make_float2(0.0f, 0.0f);
    if (valid) ct = *(const float2*)(x + (pbase + tid) * 18 + 16);

    // ---- stage weights into LDS (scalar repack into float4 chunks) ----
    float* wf = (float*)wlds;
    for (int e = tid; e < NMODELS * WPM; e += BLOCK) {
        const int m = e / WPM, k = e % WPM;
        float v;
        if (k < 102)      v = W1[m * 102 + k];
        else if (k < 108) v = b1[m * 6 + (k - 102)];
        else if (k < 204) v = W2[m * 96 + (k - 108)];
        else              v = b2[m * 16 + (k - 204)];
        wf[(k >> 2) * (NMODELS * 4) + m * 4 + (k & 3)] = v;
    }
    __syncthreads();   // hist zeroed + weights staged

    // ---- route + histogram ----
    int mid = 0, myoff = 0;
    if (valid) {
        const int c = (int)ct.x;
        const float t = ct.y;
        int bucket = (int)floorf(t * 8.0f);
        bucket = bucket < 0 ? 0 : (bucket > 7 ? 7 : bucket);
        mid = (c == 0) ? 0 : 1 + (c - 1) * 8 + bucket;
        myoff = atomicAdd(&hist[mid], 1);
    }
    __syncthreads();

    // ---- exclusive scan (65 elems, thread 0; co-resident block overlaps) ----
    if (tid == 0) {
        int acc = 0;
        for (int m = 0; m < NMODELS; ++m) { base[m] = acc; acc += hist[m]; }
    }
    __syncthreads();

    // ---- scatter sorted point list ----
    if (valid) bidx[base[mid] + myoff] = ((unsigned)mid << 16) | (unsigned)tid;
    __syncthreads();

    if (!valid) return;   // slots >= nvalid are unwritten

    const unsigned en = bidx[tid];
    const int src = (int)(en & 0xffffu);
    const int pm  = (int)(en >> 16);

    // ---- re-read x row (divergent within block's 72KB window, L2-hot) ----
    const float2* xr = (const float2*)(x + (pbase + src) * 18);
    float xf[18];
    #pragma unroll
    for (int i = 0; i < 9; ++i) {
        float2 v = xr[i];
        xf[2 * i]     = v.x;
        xf[2 * i + 1] = v.y;
    }
    const float t = xf[17];

    #define CH(cc) wlds[cc][pm]

    // ---- layer 1: h = relu(xin @ W1 + b1), xin = [data[0..15], t] ----
    float h[6];
    {
        float4 c24 = CH(24);
        float4 c25 = CH(25);
        float4 c26 = CH(26);
        h[0] = fmaf(t, c24.x, c25.z);
        h[1] = fmaf(t, c24.y, c25.w);
        h[2] = fmaf(t, c24.z, c26.x);
        h[3] = fmaf(t, c24.w, c26.y);
        h[4] = fmaf(t, c25.x, c26.z);
        h[5] = fmaf(t, c25.y, c26.w);
    }
    #pragma unroll
    for (int r = 0; r < 8; ++r) {
        float4 a = CH(3 * r + 0);
        float4 b = CH(3 * r + 1);
        float4 d = CH(3 * r + 2);
        const float x0 = xf[2 * r], x1 = xf[2 * r + 1];
        h[0] = fmaf(x0, a.x, h[0]);
        h[1] = fmaf(x0, a.y, h[1]);
        h[2] = fmaf(x0, a.z, h[2]);
        h[3] = fmaf(x0, a.w, h[3]);
        h[4] = fmaf(x0, b.x, h[4]);
        h[5] = fmaf(x0, b.y, h[5]);
        h[0] = fmaf(x1, b.z, h[0]);
        h[1] = fmaf(x1, b.w, h[1]);
        h[2] = fmaf(x1, d.x, h[2]);
        h[3] = fmaf(x1, d.y, h[3]);
        h[4] = fmaf(x1, d.z, h[4]);
        h[5] = fmaf(x1, d.w, h[5]);
    }
    #pragma unroll
    for (int j = 0; j < 6; ++j) h[j] = h[j] > 0.0f ? h[j] : 0.0f;

    // ---- layer 2: out = h @ W2 + b2 ----
    float o[16];
    #pragma unroll
    for (int g = 0; g < 4; ++g) {
        float4 v = CH(51 + g);
        o[4 * g + 0] = v.x;
        o[4 * g + 1] = v.y;
        o[4 * g + 2] = v.z;
        o[4 * g + 3] = v.w;
    }
    #pragma unroll
    for (int j = 0; j < 6; ++j) {
        const float hj = h[j];
        #pragma unroll
        for (int g = 0; g < 4; ++g) {
            float4 v = CH(27 + 4 * j + g);
            o[4 * g + 0] = fmaf(hj, v.x, o[4 * g + 0]);
            o[4 * g + 1] = fmaf(hj, v.y, o[4 * g + 1]);
            o[4 * g + 2] = fmaf(hj, v.z, o[4 * g + 2]);
            o[4 * g + 3] = fmaf(hj, v.w, o[4 * g + 3]);
        }
    }
    #undef CH

    // ---- store to ORIGINAL position (full 64B line per lane) ----
    float4* orow = (float4*)(out + (pbase + src) * 16);
    #pragma unroll
    for (int g = 0; g < 4; ++g)
        orow[g] = make_float4(o[4 * g], o[4 * g + 1], o[4 * g + 2], o[4 * g + 3]);
}

extern "C" void kernel_launch(void* const* d_in, const int* in_sizes, int n_in,
                              void* d_out, int out_size, void* d_ws, size_t ws_size,
                              hipStream_t stream) {
    const float* x  = (const float*)d_in[0];
    const float* W1 = (const float*)d_in[1];
    const float* b1 = (const float*)d_in[2];
    const float* W2 = (const float*)d_in[3];
    const float* b2 = (const float*)d_in[4];
    float* out = (float*)d_out;

    const int npts = in_sizes[0] / 18;
    const int grid = (npts + BLOCK - 1) / BLOCK;
    mvf_kernel<<<grid, BLOCK, 0, stream>>>(x, W1, b1, W2, b2, out, npts);
}

// Round 10
// 57.053 us; speedup vs baseline: 1.0889x; 1.0889x over previous
//
#include <hip/hip_runtime.h>

// MultiVectorFieldModel: per-point routed tiny MLP (17 -> 6 -> 16), 65 models.
//
// R9 design: block-local counting sort by mid (R8, proven: conflicts 5.1M->286K)
// + LDS x-exchange (fixes R8's divergent global x re-read) + bf16 pair table
// consumed via v_dot2_f32_bf16 (fp32 accumulate, no unpack ops).
//
// Weight table: 30 uint4 chunks per model, model-minor [chunk][model]:
//   chunks 0..11 : W1 column j = chunks 2j,2j+1; pair q = (W1[2q][j],W1[2q+1][j])
//   chunk  12    : (Wt[j], b1[j]) pairs, j=0..3   (Wt = W1 row 16, the t row)
//   chunk  13    : (Wt[j], b1[j]) pairs, j=4..5; slots 2,3 zero
//   chunks 14..29: d = c-14: pairs (W2[0][d],W2[1][d]),(W2[2][d],W2[3][d]),
//                  (W2[4][d],W2[5][d]),(b2[d],0)  -> dotted with
//                  (h0,h1),(h2,h3),(h4,h5),(1.0,0)
// layer1 j:  h_j = dot2(xp8,(Wt_j,b1_j)) + sum_q dot2(xp_q, w1pair)   [9 dot2]
// layer2 d:  o_d = 4 dot2                                             [64 dot2]
//
// LDS: table 31200B + x-exchange [9][1024] u32 36864B + bidx 4096B + hist/base
// 520B = 72680B -> 2 blocks/CU, 32 waves/CU.
//
// Cross-round model: divergent-address ds_read_b128 costs ~33cy of LDS pipe
// (R2/R7: 46us = 61 waves x 55 reads x 33cy); sorted mids -> ~10cy. R8's loss
// was the divergent GLOBAL x re-read; exchanging x through LDS (coalesced
// write by owner, near-conflict-free b32 permuted read) removes it.
// R3 lesson stands: never force VGPR cap 64 (spill disaster) -> (1024,4).

#define NMODELS 65
#define NCHUNK 30
#define BLOCK 1024

__device__ inline unsigned f2bf(float f) {
    unsigned u = __builtin_bit_cast(unsigned, f);
    u += 0x7fffu + ((u >> 16) & 1u);   // round-to-nearest-even
    return u >> 16;
}
__device__ inline float dot2bf(unsigned a, unsigned b, float c) {
    float r;
    asm("v_dot2_f32_bf16 %0, %1, %2, %3" : "=v"(r) : "v"(a), "v"(b), "v"(c));
    return r;
}
__device__ inline unsigned cvtpk(float lo, float hi) {
    unsigned r;
    asm("v_cvt_pk_bf16_f32 %0, %1, %2" : "=v"(r) : "v"(lo), "v"(hi));
    return r;
}

__global__ __launch_bounds__(BLOCK, 4) void mvf_kernel(
    const float* __restrict__ x,
    const float* __restrict__ W1,
    const float* __restrict__ b1,
    const float* __restrict__ W2,
    const float* __restrict__ b2,
    float* __restrict__ out,
    int npts)
{
    __shared__ unsigned wlds[NCHUNK * NMODELS * 4];   // 31200 B
    __shared__ unsigned xlds[9 * BLOCK];              // 36864 B
    __shared__ unsigned bidx[BLOCK];                  // 4096 B
    __shared__ int hist[NMODELS];                     // 260 B
    __shared__ int base_[NMODELS];                    // 260 B

    const int tid = threadIdx.x;
    if (tid < NMODELS) hist[tid] = 0;

    const long pbase = (long)blockIdx.x * BLOCK;
    const int nvalid = min(BLOCK, npts - (int)pbase);
    const bool valid = tid < nvalid;

    // ---- own x row: 9 independent float2 loads issued early ----
    float xf[18];
    if (valid) {
        const float2* xr = (const float2*)(x + (pbase + tid) * 18);
        #pragma unroll
        for (int i = 0; i < 9; ++i) {
            float2 v = xr[i];
            xf[2 * i] = v.x; xf[2 * i + 1] = v.y;
        }
    } else {
        #pragma unroll
        for (int i = 0; i < 18; ++i) xf[i] = 0.0f;
    }

    // ---- stage weight table: fp32 -> bf16 pairs, model-minor chunks ----
    for (int e = tid; e < NMODELS * NCHUNK * 4; e += BLOCK) {
        const int m = e / (NCHUNK * 4);
        const int r = e - m * (NCHUNK * 4);
        const int c = r >> 2, s = r & 3;
        float flo, fhi;
        if (c < 12) {
            const int j = c >> 1;
            const int q = (c & 1) * 4 + s;      // x-pair index 0..7
            flo = W1[m * 102 + (2 * q) * 6 + j];
            fhi = W1[m * 102 + (2 * q + 1) * 6 + j];
        } else if (c == 12) {
            flo = W1[m * 102 + 96 + s];
            fhi = b1[m * 6 + s];
        } else if (c == 13) {
            if (s < 2) { flo = W1[m * 102 + 96 + 4 + s]; fhi = b1[m * 6 + 4 + s]; }
            else       { flo = 0.0f; fhi = 0.0f; }
        } else {
            const int d = c - 14;
            if (s < 3) {
                flo = W2[m * 96 + (2 * s) * 16 + d];
                fhi = W2[m * 96 + (2 * s + 1) * 16 + d];
            } else {
                flo = b2[m * 16 + d];
                fhi = 0.0f;
            }
        }
        wlds[c * (NMODELS * 4) + m * 4 + s] = f2bf(flo) | (f2bf(fhi) << 16);
    }
    __syncthreads();   // hist zeroed + table staged

    // ---- route + histogram + write x (bf16 pairs) to exchange ----
    int mid = 0, myoff = 0;
    if (valid) {
        const float t = xf[17];
        const int c = (int)xf[16];
        int bucket = (int)floorf(t * 8.0f);
        bucket = bucket < 0 ? 0 : (bucket > 7 ? 7 : bucket);
        mid = (c == 0) ? 0 : 1 + (c - 1) * 8 + bucket;
        myoff = atomicAdd(&hist[mid], 1);
        #pragma unroll
        for (int k = 0; k < 8; ++k)
            xlds[k * BLOCK + tid] = cvtpk(xf[2 * k], xf[2 * k + 1]);
        xlds[8 * BLOCK + tid] = cvtpk(t, 1.0f);   // (t, 1) pair
    }
    __syncthreads();

    // ---- exclusive scan over 65 counts ----
    if (tid == 0) {
        int acc = 0;
        for (int m = 0; m < NMODELS; ++m) { base_[m] = acc; acc += hist[m]; }
    }
    __syncthreads();

    // ---- scatter sorted point list ----
    if (valid) bidx[base_[mid] + myoff] = ((unsigned)mid << 16) | (unsigned)tid;
    __syncthreads();

    if (!valid) return;   // no barriers after this point

    const unsigned en = bidx[tid];
    const int src = (int)(en & 0xffffu);
    const int pm  = (int)(en >> 16);

    // ---- gather x pairs from exchange (b32, ~64 distinct addrs ~2/bank) ----
    unsigned xp[9];
    #pragma unroll
    for (int k = 0; k < 9; ++k) xp[k] = xlds[k * BLOCK + src];

    const uint4* wl4 = (const uint4*)wlds;
    #define CH(cc) wl4[(cc) * NMODELS + pm]

    // ---- layer 1: h_j = (t,1)(Wt_j,b1_j) + sum_q xp_q . w1pair ----
    float h[6];
    {
        uint4 cA = CH(12), cB = CH(13);
        h[0] = dot2bf(xp[8], cA.x, 0.0f);
        h[1] = dot2bf(xp[8], cA.y, 0.0f);
        h[2] = dot2bf(xp[8], cA.z, 0.0f);
        h[3] = dot2bf(xp[8], cA.w, 0.0f);
        h[4] = dot2bf(xp[8], cB.x, 0.0f);
        h[5] = dot2bf(xp[8], cB.y, 0.0f);
    }
    #pragma unroll
    for (int j = 0; j < 6; ++j) {
        uint4 A = CH(2 * j);
        uint4 B = CH(2 * j + 1);
        float a = h[j];
        a = dot2bf(xp[0], A.x, a);
        a = dot2bf(xp[1], A.y, a);
        a = dot2bf(xp[2], A.z, a);
        a = dot2bf(xp[3], A.w, a);
        a = dot2bf(xp[4], B.x, a);
        a = dot2bf(xp[5], B.y, a);
        a = dot2bf(xp[6], B.z, a);
        a = dot2bf(xp[7], B.w, a);
        h[j] = a > 0.0f ? a : 0.0f;
    }

    // ---- pack h into bf16 pairs ----
    unsigned hp0 = cvtpk(h[0], h[1]);
    unsigned hp1 = cvtpk(h[2], h[3]);
    unsigned hp2 = cvtpk(h[4], h[5]);
    const unsigned hp3 = 0x00003F80u;   // (1.0bf16, 0)

    // ---- layer 2: o_d = hp.(W2 column-pairs) + 1.0*b2_d ----
    float o[16];
    #pragma unroll
    for (int d = 0; d < 16; ++d) {
        uint4 W = CH(14 + d);
        float a = dot2bf(hp0, W.x, 0.0f);
        a = dot2bf(hp1, W.y, a);
        a = dot2bf(hp2, W.z, a);
        a = dot2bf(hp3, W.w, a);
        o[d] = a;
    }
    #undef CH

    // ---- store to ORIGINAL position (full 64B line per lane) ----
    float4* orow = (float4*)(out + (pbase + src) * 16);
    #pragma unroll
    for (int g = 0; g < 4; ++g)
        orow[g] = make_float4(o[4 * g], o[4 * g + 1], o[4 * g + 2], o[4 * g + 3]);
}

extern "C" void kernel_launch(void* const* d_in, const int* in_sizes, int n_in,
                              void* d_out, int out_size, void* d_ws, size_t ws_size,
                              hipStream_t stream) {
    const float* x  = (const float*)d_in[0];
    const float* W1 = (const float*)d_in[1];
    const float* b1 = (const float*)d_in[2];
    const float* W2 = (const float*)d_in[3];
    const float* b2 = (const float*)d_in[4];
    float* out = (float*)d_out;

    const int npts = in_sizes[0] / 18;
    const int grid = (npts + BLOCK - 1) / BLOCK;
    mvf_kernel<<<grid, BLOCK, 0, stream>>>(x, W1, b1, W2, b2, out, npts);
}

// Round 11
// 56.639 us; speedup vs baseline: 1.0969x; 1.0073x over previous
//
#include <hip/hip_runtime.h>

// MultiVectorFieldModel: per-point routed tiny MLP (17 -> 6 -> 16), 65 models.
//
// R9 design: block-local counting sort by mid (R8, proven: conflicts 5.1M->286K)
// + LDS x-exchange (fixes R8's divergent global x re-read) + bf16 pair table
// consumed via v_dot2_f32_bf16 (fp32 accumulate, no unpack ops).
//
// Weight table: 30 uint4 chunks per model, model-minor [chunk][model]:
//   chunks 0..11 : W1 column j = chunks 2j,2j+1; pair q = (W1[2q][j],W1[2q+1][j])
//   chunk  12    : (Wt[j], b1[j]) pairs, j=0..3   (Wt = W1 row 16, the t row)
//   chunk  13    : (Wt[j], b1[j]) pairs, j=4..5; slots 2,3 zero
//   chunks 14..29: d = c-14: pairs (W2[0][d],W2[1][d]),(W2[2][d],W2[3][d]),
//                  (W2[4][d],W2[5][d]),(b2[d],0)  -> dotted with
//                  (h0,h1),(h2,h3),(h4,h5),(1.0,0)
// layer1 j:  h_j = dot2(xp8,(Wt_j,b1_j)) + sum_q dot2(xp_q, w1pair)   [9 dot2]
// layer2 d:  o_d = 4 dot2                                             [64 dot2]
//
// LDS: table 31200B + x-exchange [9][1024] u32 36864B + bidx 4096B + hist/base
// 520B = 72680B -> 2 blocks/CU, 32 waves/CU.
//
// Cross-round model: divergent-address ds_read_b128 costs ~33cy of LDS pipe
// (R2/R7: 46us = 61 waves x 55 reads x 33cy); sorted mids -> ~10cy. R8's loss
// was the divergent GLOBAL x re-read; exchanging x through LDS (coalesced
// write by owner, near-conflict-free b32 permuted read) removes it.
// R3 lesson stands: never force VGPR cap 64 (spill disaster) -> (1024,4).

#define NMODELS 65
#define NCHUNK 30
#define BLOCK 1024

__device__ inline unsigned f2bf(float f) {
    unsigned u = __builtin_bit_cast(unsigned, f);
    u += 0x7fffu + ((u >> 16) & 1u);   // round-to-nearest-even
    return u >> 16;
}
__device__ inline float dot2bf(unsigned a, unsigned b, float c) {
    float r;
    asm("v_dot2_f32_bf16 %0, %1, %2, %3" : "=v"(r) : "v"(a), "v"(b), "v"(c));
    return r;
}
__device__ inline unsigned cvtpk(float lo, float hi) {
    unsigned r;
    asm("v_cvt_pk_bf16_f32 %0, %1, %2" : "=v"(r) : "v"(lo), "v"(hi));
    return r;
}

__global__ __launch_bounds__(BLOCK, 4) void mvf_kernel(
    const float* __restrict__ x,
    const float* __restrict__ W1,
    const float* __restrict__ b1,
    const float* __restrict__ W2,
    const float* __restrict__ b2,
    float* __restrict__ out,
    int npts)
{
    __shared__ unsigned wlds[NCHUNK * NMODELS * 4];   // 31200 B
    __shared__ unsigned xlds[9 * BLOCK];              // 36864 B
    __shared__ unsigned bidx[BLOCK];                  // 4096 B
    __shared__ int hist[NMODELS];                     // 260 B
    __shared__ int base_[NMODELS];                    // 260 B

    const int tid = threadIdx.x;
    if (tid < NMODELS) hist[tid] = 0;

    const long pbase = (long)blockIdx.x * BLOCK;
    const int nvalid = min(BLOCK, npts - (int)pbase);
    const bool valid = tid < nvalid;

    // ---- own x row: 9 independent float2 loads issued early ----
    float xf[18];
    if (valid) {
        const float2* xr = (const float2*)(x + (pbase + tid) * 18);
        #pragma unroll
        for (int i = 0; i < 9; ++i) {
            float2 v = xr[i];
            xf[2 * i] = v.x; xf[2 * i + 1] = v.y;
        }
    } else {
        #pragma unroll
        for (int i = 0; i < 18; ++i) xf[i] = 0.0f;
    }

    // ---- stage weight table: fp32 -> bf16 pairs, model-minor chunks ----
    for (int e = tid; e < NMODELS * NCHUNK * 4; e += BLOCK) {
        const int m = e / (NCHUNK * 4);
        const int r = e - m * (NCHUNK * 4);
        const int c = r >> 2, s = r & 3;
        float flo, fhi;
        if (c < 12) {
            const int j = c >> 1;
            const int q = (c & 1) * 4 + s;      // x-pair index 0..7
            flo = W1[m * 102 + (2 * q) * 6 + j];
            fhi = W1[m * 102 + (2 * q + 1) * 6 + j];
        } else if (c == 12) {
            flo = W1[m * 102 + 96 + s];
            fhi = b1[m * 6 + s];
        } else if (c == 13) {
            if (s < 2) { flo = W1[m * 102 + 96 + 4 + s]; fhi = b1[m * 6 + 4 + s]; }
            else       { flo = 0.0f; fhi = 0.0f; }
        } else {
            const int d = c - 14;
            if (s < 3) {
                flo = W2[m * 96 + (2 * s) * 16 + d];
                fhi = W2[m * 96 + (2 * s + 1) * 16 + d];
            } else {
                flo = b2[m * 16 + d];
                fhi = 0.0f;
            }
        }
        wlds[c * (NMODELS * 4) + m * 4 + s] = f2bf(flo) | (f2bf(fhi) << 16);
    }
    __syncthreads();   // hist zeroed + table staged

    // ---- route + histogram + write x (bf16 pairs) to exchange ----
    int mid = 0, myoff = 0;
    if (valid) {
        const float t = xf[17];
        const int c = (int)xf[16];
        int bucket = (int)floorf(t * 8.0f);
        bucket = bucket < 0 ? 0 : (bucket > 7 ? 7 : bucket);
        mid = (c == 0) ? 0 : 1 + (c - 1) * 8 + bucket;
        myoff = atomicAdd(&hist[mid], 1);
        #pragma unroll
        for (int k = 0; k < 8; ++k)
            xlds[k * BLOCK + tid] = cvtpk(xf[2 * k], xf[2 * k + 1]);
        xlds[8 * BLOCK + tid] = cvtpk(t, 1.0f);   // (t, 1) pair
    }
    __syncthreads();

    // ---- exclusive scan over 65 counts ----
    if (tid == 0) {
        int acc = 0;
        for (int m = 0; m < NMODELS; ++m) { base_[m] = acc; acc += hist[m]; }
    }
    __syncthreads();

    // ---- scatter sorted point list ----
    if (valid) bidx[base_[mid] + myoff] = ((unsigned)mid << 16) | (unsigned)tid;
    __syncthreads();

    if (!valid) return;   // no barriers after this point

    const unsigned en = bidx[tid];
    const int src = (int)(en & 0xffffu);
    const int pm  = (int)(en >> 16);

    // ---- gather x pairs from exchange (b32, ~64 distinct addrs ~2/bank) ----
    unsigned xp[9];
    #pragma unroll
    for (int k = 0; k < 9; ++k) xp[k] = xlds[k * BLOCK + src];

    const uint4* wl4 = (const uint4*)wlds;
    #define CH(cc) wl4[(cc) * NMODELS + pm]

    // ---- layer 1: h_j = (t,1)(Wt_j,b1_j) + sum_q xp_q . w1pair ----
    float h[6];
    {
        uint4 cA = CH(12), cB = CH(13);
        h[0] = dot2bf(xp[8], cA.x, 0.0f);
        h[1] = dot2bf(xp[8], cA.y, 0.0f);
        h[2] = dot2bf(xp[8], cA.z, 0.0f);
        h[3] = dot2bf(xp[8], cA.w, 0.0f);
        h[4] = dot2bf(xp[8], cB.x, 0.0f);
        h[5] = dot2bf(xp[8], cB.y, 0.0f);
    }
    #pragma unroll
    for (int j = 0; j < 6; ++j) {
        uint4 A = CH(2 * j);
        uint4 B = CH(2 * j + 1);
        float a = h[j];
        a = dot2bf(xp[0], A.x, a);
        a = dot2bf(xp[1], A.y, a);
        a = dot2bf(xp[2], A.z, a);
        a = dot2bf(xp[3], A.w, a);
        a = dot2bf(xp[4], B.x, a);
        a = dot2bf(xp[5], B.y, a);
        a = dot2bf(xp[6], B.z, a);
        a = dot2bf(xp[7], B.w, a);
        h[j] = a > 0.0f ? a : 0.0f;
    }

    // ---- pack h into bf16 pairs ----
    unsigned hp0 = cvtpk(h[0], h[1]);
    unsigned hp1 = cvtpk(h[2], h[3]);
    unsigned hp2 = cvtpk(h[4], h[5]);
    const unsigned hp3 = 0x00003F80u;   // (1.0bf16, 0)

    // ---- layer 2: o_d = hp.(W2 column-pairs) + 1.0*b2_d ----
    float o[16];
    #pragma unroll
    for (int d = 0; d < 16; ++d) {
        uint4 W = CH(14 + d);
        float a = dot2bf(hp0, W.x, 0.0f);
        a = dot2bf(hp1, W.y, a);
        a = dot2bf(hp2, W.z, a);
        a = dot2bf(hp3, W.w, a);
        o[d] = a;
    }
    #undef CH

    // ---- store to ORIGINAL position (full 64B line per lane) ----
    float4* orow = (float4*)(out + (pbase + src) * 16);
    #pragma unroll
    for (int g = 0; g < 4; ++g)
        orow[g] = make_float4(o[4 * g], o[4 * g + 1], o[4 * g + 2], o[4 * g + 3]);
}

extern "C" void kernel_launch(void* const* d_in, const int* in_sizes, int n_in,
                              void* d_out, int out_size, void* d_ws, size_t ws_size,
                              hipStream_t stream) {
    const float* x  = (const float*)d_in[0];
    const float* W1 = (const float*)d_in[1];
    const float* b1 = (const float*)d_in[2];
    const float* W2 = (const float*)d_in[3];
    const float* b2 = (const float*)d_in[4];
    float* out = (float*)d_out;

    const int npts = in_sizes[0] / 18;
    const int grid = (npts + BLOCK - 1) / BLOCK;
    mvf_kernel<<<grid, BLOCK, 0, stream>>>(x, W1, b1, W2, b2, out, npts);
}